// Round 8
// baseline (601.663 us; speedup 1.0000x reference)
//
#include <hip/hip_runtime.h>

#define B_ 64
#define S_ 1024
#define NT 48
#define DM 512
#define TT 50

// ---------------- K1: tag_vec = F @ W^T / sqrt(512) ----------------
__global__ __launch_bounds__(256) void k_tagvec(const float* __restrict__ F,
                                                const float* __restrict__ Wm,
                                                float* __restrict__ out) {
  __shared__ float fs[128][68];
  __shared__ float wsh[48][68];
  const int t = threadIdx.x;
  const int rowBase = blockIdx.x * 128;
  const int jg = t & 3;
  const int rq = t >> 2;
  const int r0 = rq * 2, r1 = r0 + 1;
  float acc0[12];
  float acc1[12];
#pragma unroll
  for (int q = 0; q < 12; ++q) { acc0[q] = 0.f; acc1[q] = 0.f; }
  for (int kc = 0; kc < DM; kc += 64) {
    __syncthreads();
#pragma unroll
    for (int i2 = 0; i2 < 8; ++i2) {
      int f = t + i2 * 256;
      int row = f >> 4, kk = f & 15;
      float4 v = *(const float4*)(F + (size_t)(rowBase + row) * DM + kc + kk * 4);
      *(float4*)&fs[row][kk * 4] = v;
    }
#pragma unroll
    for (int i2 = 0; i2 < 3; ++i2) {
      int f = t + i2 * 256;
      int row = f >> 4, kk = f & 15;
      float4 v = *(const float4*)(Wm + (size_t)row * DM + kc + kk * 4);
      *(float4*)&wsh[row][kk * 4] = v;
    }
    __syncthreads();
#pragma unroll 4
    for (int k4 = 0; k4 < 16; ++k4) {
      float4 a0 = *(const float4*)&fs[r0][k4 * 4];
      float4 a1 = *(const float4*)&fs[r1][k4 * 4];
#pragma unroll
      for (int jj = 0; jj < 12; ++jj) {
        float4 w = *(const float4*)&wsh[jg * 12 + jj][k4 * 4];
        acc0[jj] += a0.x * w.x + a0.y * w.y + a0.z * w.z + a0.w * w.w;
        acc1[jj] += a1.x * w.x + a1.y * w.y + a1.z * w.z + a1.w * w.w;
      }
    }
  }
  const float sc = 0.044194173824159216f;
  size_t base0 = (size_t)(rowBase + r0) * NT + jg * 12;
  size_t base1 = (size_t)(rowBase + r1) * NT + jg * 12;
#pragma unroll
  for (int q = 0; q < 3; ++q) {
    float4 o0 = make_float4(acc0[q*4]*sc, acc0[q*4+1]*sc, acc0[q*4+2]*sc, acc0[q*4+3]*sc);
    float4 o1 = make_float4(acc1[q*4]*sc, acc1[q*4+1]*sc, acc1[q*4+2]*sc, acc1[q*4+3]*sc);
    *(float4*)(out + base0 + q*4) = o0;
    *(float4*)(out + base1 + q*4) = o1;
  }
}

// ---------------- K2: gold-path score per batch ----------------
__global__ __launch_bounds__(256) void k_score(const float* __restrict__ tg,
                                               const int* __restrict__ y,
                                               const unsigned char* __restrict__ mask,
                                               const float* __restrict__ trans,
                                               float* __restrict__ scoreOut) {
  const int b = blockIdx.x, t = threadIdx.x;
  const int* yb = y + (size_t)b * S_;
  const unsigned char* mbp = mask + (size_t)b * S_;
  float part = 0.f;
  int cnt = 0;
  for (int s = t; s < S_; s += 256) {
    int ys = yb[s];
    int ms = mbp[s];
    float bm = ms ? 0.f : 1.f;
    int yy = ms ? 0 : ys;
    part += tg[((size_t)b * S_ + s) * NT + yy] * bm;
    if (s >= 1) part += trans[yb[s - 1] * TT + ys] * bm;
    cnt += ms ? 1 : 0;
  }
  for (int d = 1; d < 64; d <<= 1) {
    part += __shfl_xor(part, d);
    cnt += __shfl_xor(cnt, d);
  }
  __shared__ float pw[4];
  __shared__ int cw[4];
  int wid = t >> 6;
  if ((t & 63) == 0) { pw[wid] = part; cw[wid] = cnt; }
  __syncthreads();
  if (t == 0) {
    float tot = pw[0] + pw[1] + pw[2] + pw[3];
    int c = cw[0] + cw[1] + cw[2] + cw[3];
    int L = S_ - 1 - c;
    tot += trans[NT * TT + yb[0]];
    tot += trans[yb[L] * TT + (NT + 1)];
    scoreOut[b] = tot;
  }
}

// ---------------- K3: FUSED forward+Viterbi serial scan, one wave per batch ----------------
// Both chains interleave in one instruction stream: each fills the other's
// dependent-issue gaps and DS-latency stalls. Shared e-chunk staging and a
// single ds_read of e[A] feeds both recurrences.
__global__ __launch_bounds__(64, 1) void k_scan(const float* __restrict__ tg,
                                                const unsigned char* __restrict__ mask,
                                                const float* __restrict__ trans,
                                                const float* __restrict__ score,
                                                float* __restrict__ ckpt,
                                                int* __restrict__ nowbuf,
                                                float* __restrict__ out) {
  alignas(16) __shared__ float pls_f[64];
  alignas(16) __shared__ float pls_v[64];
  alignas(16) __shared__ float els[2][64 * NT];  // shared e-chunks, 24 KB
  __shared__ float bmL[S_ + 8];
  __shared__ float rbuf[256];

  const int t = threadIdx.x;
  const int b = blockIdx.x;
  const int jc = (t < NT) ? t : (NT - 1);
  const float* tgb = tg + (size_t)b * S_ * NT;

  int cnt = 0;
  for (int m = t; m < S_; m += 64) {
    unsigned char mv = mask[(size_t)b * S_ + m];
    bmL[m] = mv ? 0.f : 1.f;
    cnt += mv ? 1 : 0;
  }
  if (t < 8) bmL[S_ + t] = 0.f;
#pragma unroll
  for (int d = 1; d < 64; d <<= 1) cnt += __shfl_xor(cnt, d);
  const int L = S_ - 1 - cnt;
  __syncthreads();

  // stage e-chunk 0 into regs
  float4 st[12];
#pragma unroll
  for (int k = 0; k < 12; ++k) st[k] = *(const float4*)(tgb + (k * 64 + t) * 4);

  float Tcol[NT];
#pragma unroll
  for (int i = 0; i < NT; ++i) Tcol[i] = trans[i * TT + jc];
  float Ecol[NT];
#pragma unroll
  for (int i = 0; i < NT; ++i) Ecol[i] = __expf(Tcol[i]);
#pragma unroll
  for (int i = 0; i < NT; ++i) asm("" : "+v"(Tcol[i]));
#pragma unroll
  for (int i = 0; i < NT; ++i) asm("" : "+v"(Ecol[i]));

  const float startj = trans[NT * TT + jc];
  const float e0 = tgb[jc];
  pls_f[t] = __expf(startj + e0 * bmL[0]);  // pe_0
  const float best0 = startj + e0;          // viterbi b_0 (unmasked e, per reference)
  pls_v[t] = best0;
  if (t < NT) ckpt[((size_t)b * 128) * NT + t] = best0;
  float fin = best0;  // valid if L == 0
  float pfinal = 0.f;

  // commit chunk 0, prefetch chunk 1
#pragma unroll
  for (int k = 0; k < 12; ++k) *(float4*)&els[0][(k * 64 + t) * 4] = st[k];
#pragma unroll
  for (int k = 0; k < 12; ++k) st[k] = *(const float4*)(tgb + 3072 + (k * 64 + t) * 4);

  // STEP(A): viterbi step s=A  AND  forward step s=A-1 (produces pe_A)
#define STEP(A, RENORM, DOCKPT)                                                \
    {                                                                          \
      float ev = els[((A) >> 6) & 1][((A) & 63) * NT + jc];                    \
      /* --- viterbi half --- */                                               \
      float4 bv[12];                                                           \
      _Pragma("unroll")                                                        \
      for (int q = 0; q < 12; ++q) bv[q] = *(const float4*)&pls_v[4 * q];      \
      float cm[12];                                                            \
      _Pragma("unroll")                                                        \
      for (int q = 0; q < 12; ++q) {                                           \
        float c0 = bv[q].x + Tcol[4 * q + 0];                                  \
        float c1 = bv[q].y + Tcol[4 * q + 1];                                  \
        float c2 = bv[q].z + Tcol[4 * q + 2];                                  \
        float c3 = bv[q].w + Tcol[4 * q + 3];                                  \
        cm[q] = fmaxf(fmaxf(c0, c1), fmaxf(c2, c3));                           \
      }                                                                        \
      float vg0 = fmaxf(fmaxf(cm[0], cm[1]), cm[2]);                           \
      float vg1 = fmaxf(fmaxf(cm[3], cm[4]), cm[5]);                           \
      float vg2 = fmaxf(fmaxf(cm[6], cm[7]), cm[8]);                           \
      float vg3 = fmaxf(fmaxf(cm[9], cm[10]), cm[11]);                         \
      float Mv = fmaxf(fmaxf(vg0, vg1), fmaxf(vg2, vg3));                      \
      float bnew = Mv + ev;                                                    \
      /* --- forward half --- */                                               \
      float4 bf[12];                                                           \
      _Pragma("unroll")                                                        \
      for (int q = 0; q < 12; ++q) bf[q] = *(const float4*)&pls_f[4 * q];      \
      float m1r = bmL[(A)];                                                    \
      int m1b = __builtin_amdgcn_readfirstlane(__float_as_int(m1r));           \
      float Z;                                                                 \
      if (m1b != 0) {                                                          \
        float z0 = 0.f, z1 = 0.f, z2 = 0.f, z3 = 0.f;                          \
        _Pragma("unroll")                                                      \
        for (int q = 0; q < 12; ++q) {                                         \
          z0 = fmaf(bf[q].x, Ecol[4 * q + 0], z0);                             \
          z1 = fmaf(bf[q].y, Ecol[4 * q + 1], z1);                             \
          z2 = fmaf(bf[q].z, Ecol[4 * q + 2], z2);                             \
          z3 = fmaf(bf[q].w, Ecol[4 * q + 3], z3);                             \
        }                                                                      \
        Z = (z0 + z1) + (z2 + z3);                                             \
      } else {                                                                 \
        float z0 = 0.f, z1 = 0.f, z2 = 0.f, z3 = 0.f;                          \
        _Pragma("unroll")                                                      \
        for (int q = 0; q < 12; ++q) {                                         \
          z0 += bf[q].x; z1 += bf[q].y; z2 += bf[q].z; z3 += bf[q].w;          \
        }                                                                      \
        Z = (z0 + z1) + (z2 + z3);                                             \
      }                                                                        \
      float pnew = Z;                                                          \
      if (RENORM) {                                                            \
        float mm[12];                                                          \
        _Pragma("unroll")                                                      \
        for (int q = 0; q < 12; ++q)                                           \
          mm[q] = fmaxf(fmaxf(bf[q].x, bf[q].y), fmaxf(bf[q].z, bf[q].w));     \
        float g0 = fmaxf(fmaxf(mm[0], mm[1]), mm[2]);                          \
        float g1 = fmaxf(fmaxf(mm[3], mm[4]), mm[5]);                          \
        float g2 = fmaxf(fmaxf(mm[6], mm[7]), mm[8]);                          \
        float g3 = fmaxf(fmaxf(mm[9], mm[10]), mm[11]);                        \
        float Mf = fmaxf(fmaxf(g0, g1), fmaxf(g2, g3));                        \
        float r = __builtin_amdgcn_rcpf(Mf);                                   \
        pnew = Z * r;                                                          \
        if (t == 0) rbuf[((A) - 1) >> 2] = r;                                  \
      }                                                                        \
      float pe = pnew * __expf(ev * m1r);                                      \
      pls_f[t] = pe;                                                           \
      pls_v[t] = bnew;                                                         \
      fin = ((A) == L) ? bnew : fin;                                           \
      if (DOCKPT && t < NT)                                                    \
        ckpt[((size_t)b * 128 + ((A) >> 3)) * NT + t] = bnew;                  \
    }

  for (int g = 0; g < 127; ++g) {
    if ((g & 7) == 7) {
      const int c = (g + 1) >> 3;
#pragma unroll
      for (int k = 0; k < 12; ++k) *(float4*)&els[c & 1][(k * 64 + t) * 4] = st[k];
      if (c < 15) {
        const float* cb = tgb + (size_t)(c + 1) * 3072;
#pragma unroll
        for (int k = 0; k < 12; ++k) st[k] = *(const float4*)(cb + (k * 64 + t) * 4);
      }
    }
#pragma unroll
    for (int kk = 0; kk < 8; ++kk) {
      STEP(8 * g + 1 + kk, (kk == 3 || kk == 7), (kk == 7))
    }
  }
#pragma unroll
  for (int kk = 0; kk < 7; ++kk) {
    STEP(1017 + kk, (kk == 3), 0)
  }
#undef STEP

  // forward final step s=1023: bm_next = 0 -> plain sum, renorm, pfinal
  {
    float4 bf[12];
#pragma unroll
    for (int q = 0; q < 12; ++q) bf[q] = *(const float4*)&pls_f[4 * q];
    float z0 = 0.f, z1 = 0.f, z2 = 0.f, z3 = 0.f;
#pragma unroll
    for (int q = 0; q < 12; ++q) {
      z0 += bf[q].x; z1 += bf[q].y; z2 += bf[q].z; z3 += bf[q].w;
    }
    float Z = (z0 + z1) + (z2 + z3);
    float mm[12];
#pragma unroll
    for (int q = 0; q < 12; ++q)
      mm[q] = fmaxf(fmaxf(bf[q].x, bf[q].y), fmaxf(bf[q].z, bf[q].w));
    float g0 = fmaxf(fmaxf(mm[0], mm[1]), mm[2]);
    float g1 = fmaxf(fmaxf(mm[3], mm[4]), mm[5]);
    float g2 = fmaxf(fmaxf(mm[6], mm[7]), mm[8]);
    float g3 = fmaxf(fmaxf(mm[9], mm[10]), mm[11]);
    float Mf = fmaxf(fmaxf(g0, g1), fmaxf(g2, g3));
    float r = __builtin_amdgcn_rcpf(Mf);
    if (t == 0) rbuf[255] = r;
    pfinal = Z * r;
  }
  // forward epilogue
  float ls = 0.f;
#pragma unroll
  for (int k = 0; k < 4; ++k) ls += __logf(rbuf[t + 64 * k]);
#pragma unroll
  for (int d = 1; d < 64; d <<= 1) ls += __shfl_xor(ls, d);
  float v = (t < NT) ? pfinal * __expf(trans[t * TT + (NT + 1)]) : 0.f;
#pragma unroll
  for (int d = 1; d < 64; d <<= 1) v += __shfl_xor(v, d);
  if (t == 0) out[b] = __logf(v) - ls - score[b];
  // viterbi epilogue
  float fv = (t < NT) ? (fin + trans[t * TT + (NT + 1)]) : -3.0e38f;
  float Mv = fv;
#pragma unroll
  for (int d = 1; d < 64; d <<= 1) Mv = fmaxf(Mv, __shfl_xor(Mv, d));
  unsigned long long ball = __ballot(fv == Mv);
  int now0 = __ffsll(ball) - 1;
  if (t == 0) nowbuf[b] = now0;
}

// ---------------- K4: segment replay -> argmax indices (bit-exact) ----------------
__global__ __launch_bounds__(256, 1) void k_idx(const float* __restrict__ tg,
                                                const float* __restrict__ ckpt,
                                                const float* __restrict__ trans,
                                                unsigned char* __restrict__ idxbuf) {
  alignas(16) __shared__ float pw4[4][64];
  const int t = threadIdx.x;
  const int w = t >> 6;
  const int l = t & 63;
  const int b = blockIdx.x;
  const int m = blockIdx.y * 4 + w;
  const int jc = (l < NT) ? l : (NT - 1);
  const float* tgb = tg + (size_t)b * S_ * NT;
  float Tcol[NT];
#pragma unroll
  for (int i = 0; i < NT; ++i) Tcol[i] = trans[i * TT + jc];
  float old = ckpt[((size_t)b * 128 + m) * NT + jc];
  float ev[8];
#pragma unroll
  for (int k = 0; k < 8; ++k) {
    int s = 8 * m + 1 + k;
    s = (s < S_) ? s : (S_ - 1);
    ev[k] = tgb[(size_t)s * NT + jc];
  }
  unsigned char* ib = idxbuf + (size_t)b * S_ * NT;
#pragma unroll
  for (int k = 0; k < 8; ++k) {
    const int s = 8 * m + 1 + k;
    if (s < S_) {
      pw4[w][l] = old;
      float4 bb[12];
#pragma unroll
      for (int q = 0; q < 12; ++q) bb[q] = *(const float4*)&pw4[w][4 * q];
      float cc[NT];
#pragma unroll
      for (int q = 0; q < 12; ++q) {
        cc[4 * q + 0] = bb[q].x + Tcol[4 * q + 0];
        cc[4 * q + 1] = bb[q].y + Tcol[4 * q + 1];
        cc[4 * q + 2] = bb[q].z + Tcol[4 * q + 2];
        cc[4 * q + 3] = bb[q].w + Tcol[4 * q + 3];
      }
      float cm[12];
#pragma unroll
      for (int q = 0; q < 12; ++q)
        cm[q] = fmaxf(fmaxf(fmaxf(cc[4 * q], cc[4 * q + 1]), cc[4 * q + 2]), cc[4 * q + 3]);
      float g0 = fmaxf(fmaxf(cm[0], cm[1]), cm[2]);
      float g1 = fmaxf(fmaxf(cm[3], cm[4]), cm[5]);
      float g2 = fmaxf(fmaxf(cm[6], cm[7]), cm[8]);
      float g3 = fmaxf(fmaxf(cm[9], cm[10]), cm[11]);
      float M = fmaxf(fmaxf(g0, g1), fmaxf(g2, g3));
      int idx = 0;
#pragma unroll
      for (int i = NT - 1; i >= 0; --i) idx = (cc[i] == M) ? i : idx;
      if (l < NT) ib[(size_t)s * NT + jc] = (unsigned char)idx;
      old = M + ev[k];
    }
  }
}

// ---------------- K5: backtrack via chunked pointer jumping ----------------
__global__ __launch_bounds__(1024) void k_btrack(const unsigned char* __restrict__ idxbuf,
                                                 const unsigned char* __restrict__ mask,
                                                 const int* __restrict__ nowbuf,
                                                 float* __restrict__ out) {
  __shared__ unsigned char idxL[S_][NT];
  __shared__ unsigned char mapc[16][NT];
  __shared__ int ELs[16];
  __shared__ int cnt_sh;
  const int t = threadIdx.x;
  const int b = blockIdx.x;
  if (t == 0) cnt_sh = 0;
  __syncthreads();
  {
    const unsigned int* src = (const unsigned int*)(idxbuf + (size_t)b * S_ * NT);
    unsigned int* dst = (unsigned int*)&idxL[t][0];
#pragma unroll
    for (int k = 0; k < 12; ++k) dst[k] = src[(size_t)t * 12 + k];
  }
  int mv = mask[(size_t)b * S_ + t] ? 1 : 0;
  unsigned long long bal = __ballot(mv);
  int wcnt = __popcll(bal);
  if ((t & 63) == 0 && wcnt) atomicAdd(&cnt_sh, wcnt);
  __syncthreads();
  const int L = S_ - 1 - cnt_sh;
  const int now0 = nowbuf[b];
  if (t < 16 * NT) {
    const int c = t / NT;
    const int g = t - c * NT;
    int cur = g;
    const int top = (c == 15) ? (S_ - 1) : (c + 1) * 64;
    const int base = c * 64;
    for (int m = top; m > base; --m) {
      if (m <= L) cur = idxL[m][cur];
    }
    mapc[c][g] = (unsigned char)cur;
  }
  __syncthreads();
  if (t == 0) {
    int e = now0;
    ELs[15] = e;
    for (int c2 = 15; c2 >= 1; --c2) {
      e = mapc[c2][e];
      ELs[c2 - 1] = e;
    }
  }
  __syncthreads();
  float* pathOut = out + B_ + (size_t)b * S_;
  if (t < 16) {
    const int c = t;
    const int top = (c == 15) ? (S_ - 1) : (c + 1) * 64;
    const int base = c * 64;
    int cu = ELs[c];
    for (int m = top; m > base; --m) {
      if (m <= L) cu = idxL[m][cu];
      int pos = m - 1;
      pathOut[pos] = (pos > L) ? -1.0f : (float)cu;
    }
  }
  if (t == 0) pathOut[S_ - 1] = (L == S_ - 1) ? (float)now0 : -1.0f;
}

extern "C" void kernel_launch(void* const* d_in, const int* in_sizes, int n_in,
                              void* d_out, int out_size, void* d_ws, size_t ws_size,
                              hipStream_t stream) {
  const float* F = (const float*)d_in[0];
  const int* y = (const int*)d_in[1];
  const unsigned char* mask = (const unsigned char*)d_in[2];
  const float* Wm = (const float*)d_in[3];
  const float* trans = (const float*)d_in[4];
  float* out = (float*)d_out;

  const size_t NTG = (size_t)B_ * S_ * NT;
  float* tg = (float*)d_ws;
  float* score = tg + NTG;
  float* ckpt = score + 64;                              // 64*128*48 floats
  int* nowbuf = (int*)(ckpt + (size_t)B_ * 128 * NT);
  unsigned char* idxbuf = (unsigned char*)(nowbuf + 64); // 64*1024*48 bytes

  k_tagvec<<<dim3((B_ * S_) / 128), dim3(256), 0, stream>>>(F, Wm, tg);
  k_score<<<dim3(B_), dim3(256), 0, stream>>>(tg, y, mask, trans, score);
  k_scan<<<dim3(B_), dim3(64), 0, stream>>>(tg, mask, trans, score, ckpt, nowbuf, out);
  k_idx<<<dim3(B_, 32), dim3(256), 0, stream>>>(tg, ckpt, trans, idxbuf);
  k_btrack<<<dim3(B_), dim3(1024), 0, stream>>>(idxbuf, mask, nowbuf, out);
}

// Round 9
// 317.981 us; speedup vs baseline: 1.8921x; 1.8921x over previous
//
#include <hip/hip_runtime.h>

#define B_ 64
#define S_ 1024
#define NT 48
#define DM 512
#define TT 50

typedef float v2f __attribute__((ext_vector_type(2)));
typedef float v4f __attribute__((ext_vector_type(4)));

// ---------------- K1: tag_vec = F @ W^T / sqrt(512) ----------------
__global__ __launch_bounds__(256) void k_tagvec(const float* __restrict__ F,
                                                const float* __restrict__ Wm,
                                                float* __restrict__ out) {
  __shared__ float fs[128][68];
  __shared__ float wsh[48][68];
  const int t = threadIdx.x;
  const int rowBase = blockIdx.x * 128;
  const int jg = t & 3;
  const int rq = t >> 2;
  const int r0 = rq * 2, r1 = r0 + 1;
  float acc0[12];
  float acc1[12];
#pragma unroll
  for (int q = 0; q < 12; ++q) { acc0[q] = 0.f; acc1[q] = 0.f; }
  for (int kc = 0; kc < DM; kc += 64) {
    __syncthreads();
#pragma unroll
    for (int i2 = 0; i2 < 8; ++i2) {
      int f = t + i2 * 256;
      int row = f >> 4, kk = f & 15;
      float4 v = *(const float4*)(F + (size_t)(rowBase + row) * DM + kc + kk * 4);
      *(float4*)&fs[row][kk * 4] = v;
    }
#pragma unroll
    for (int i2 = 0; i2 < 3; ++i2) {
      int f = t + i2 * 256;
      int row = f >> 4, kk = f & 15;
      float4 v = *(const float4*)(Wm + (size_t)row * DM + kc + kk * 4);
      *(float4*)&wsh[row][kk * 4] = v;
    }
    __syncthreads();
#pragma unroll 4
    for (int k4 = 0; k4 < 16; ++k4) {
      float4 a0 = *(const float4*)&fs[r0][k4 * 4];
      float4 a1 = *(const float4*)&fs[r1][k4 * 4];
#pragma unroll
      for (int jj = 0; jj < 12; ++jj) {
        float4 w = *(const float4*)&wsh[jg * 12 + jj][k4 * 4];
        acc0[jj] += a0.x * w.x + a0.y * w.y + a0.z * w.z + a0.w * w.w;
        acc1[jj] += a1.x * w.x + a1.y * w.y + a1.z * w.z + a1.w * w.w;
      }
    }
  }
  const float sc = 0.044194173824159216f;
  size_t base0 = (size_t)(rowBase + r0) * NT + jg * 12;
  size_t base1 = (size_t)(rowBase + r1) * NT + jg * 12;
#pragma unroll
  for (int q = 0; q < 3; ++q) {
    float4 o0 = make_float4(acc0[q*4]*sc, acc0[q*4+1]*sc, acc0[q*4+2]*sc, acc0[q*4+3]*sc);
    float4 o1 = make_float4(acc1[q*4]*sc, acc1[q*4+1]*sc, acc1[q*4+2]*sc, acc1[q*4+3]*sc);
    *(float4*)(out + base0 + q*4) = o0;
    *(float4*)(out + base1 + q*4) = o1;
  }
}

// ---------------- K2: gold-path score per batch ----------------
__global__ __launch_bounds__(256) void k_score(const float* __restrict__ tg,
                                               const int* __restrict__ y,
                                               const unsigned char* __restrict__ mask,
                                               const float* __restrict__ trans,
                                               float* __restrict__ scoreOut) {
  const int b = blockIdx.x, t = threadIdx.x;
  const int* yb = y + (size_t)b * S_;
  const unsigned char* mbp = mask + (size_t)b * S_;
  float part = 0.f;
  int cnt = 0;
  for (int s = t; s < S_; s += 256) {
    int ys = yb[s];
    int ms = mbp[s];
    float bm = ms ? 0.f : 1.f;
    int yy = ms ? 0 : ys;
    part += tg[((size_t)b * S_ + s) * NT + yy] * bm;
    if (s >= 1) part += trans[yb[s - 1] * TT + ys] * bm;
    cnt += ms ? 1 : 0;
  }
  for (int d = 1; d < 64; d <<= 1) {
    part += __shfl_xor(part, d);
    cnt += __shfl_xor(cnt, d);
  }
  __shared__ float pw[4];
  __shared__ int cw[4];
  int wid = t >> 6;
  if ((t & 63) == 0) { pw[wid] = part; cw[wid] = cnt; }
  __syncthreads();
  if (t == 0) {
    float tot = pw[0] + pw[1] + pw[2] + pw[3];
    int c = cw[0] + cw[1] + cw[2] + cw[3];
    int L = S_ - 1 - c;
    tot += trans[NT * TT + yb[0]];
    tot += trans[yb[L] * TT + (NT + 1)];
    scoreOut[b] = tot;
  }
}

// ---------------- K3: single-wave serial scans, minimal-instruction step ----------------
// blocks 0..63 forward (linear domain), 64..127 Viterbi value pass.
__global__ __launch_bounds__(64, 1) void k_scan(const float* __restrict__ tg,
                                                const unsigned char* __restrict__ mask,
                                                const float* __restrict__ trans,
                                                const float* __restrict__ score,
                                                float* __restrict__ Mbuf,
                                                int* __restrict__ nowbuf,
                                                float* __restrict__ out) {
  alignas(16) __shared__ float pls[64];
  __shared__ float bmL[S_ + 8];
  __shared__ float rbuf[256];

  const int t = threadIdx.x;
  const bool isV = blockIdx.x >= B_;
  const int b = isV ? (blockIdx.x - B_) : blockIdx.x;
  const int jc = (t < NT) ? t : (NT - 1);
  const float* tgb = tg + (size_t)b * S_ * NT;

  int cnt = 0;
  for (int m = t; m < S_; m += 64) {
    unsigned char mv = mask[(size_t)b * S_ + m];
    bmL[m] = mv ? 0.f : 1.f;
    cnt += mv ? 1 : 0;
  }
  if (t < 8) bmL[S_ + t] = 0.f;
#pragma unroll
  for (int d = 1; d < 64; d <<= 1) cnt += __shfl_xor(cnt, d);
  const int L = S_ - 1 - cnt;
  __syncthreads();

  if (!isV) {
    // ---------- forward, linear domain, pk_fma MACs ----------
    v2f E2[24];
#pragma unroll
    for (int q = 0; q < 24; ++q) {
      E2[q].x = __expf(trans[(2 * q) * TT + jc]);
      E2[q].y = __expf(trans[(2 * q + 1) * TT + jc]);
    }
    pls[t] = __expf(trans[NT * TT + jc] + tgb[jc] * bmL[0]);  // pe_0
    float ebuf[8];  // ebuf[k] = e[A], A = 8g+1+k
#pragma unroll
    for (int k = 0; k < 8; ++k) ebuf[k] = tgb[(size_t)(k + 1) * NT + jc];
    const float* ebp = tgb + (size_t)9 * NT + jc;
    float pfinal = 0.f;

    // FSTEP(KK): step s = A-1, A = 8g+1+KK; consumes pe_{A-1}, produces pe_A
#define FSTEP(KK, RENORM, DOREFILL)                                            \
    {                                                                          \
      v4f bb4[12];                                                             \
      _Pragma("unroll")                                                        \
      for (int q = 0; q < 12; ++q) bb4[q] = *(const v4f*)&pls[4 * q];          \
      const v2f* bb = (const v2f*)bb4;                                         \
      float m1r = bmp[KK];                                                     \
      int m1b = __builtin_amdgcn_readfirstlane(__float_as_int(m1r));           \
      float Z;                                                                 \
      if (m1b != 0) {                                                          \
        v2f z0 = bb[0] * E2[0], z1 = bb[1] * E2[1];                            \
        v2f z2 = bb[2] * E2[2], z3 = bb[3] * E2[3];                            \
        _Pragma("unroll")                                                      \
        for (int q = 4; q < 24; q += 4) {                                      \
          z0 = __builtin_elementwise_fma(bb[q + 0], E2[q + 0], z0);            \
          z1 = __builtin_elementwise_fma(bb[q + 1], E2[q + 1], z1);            \
          z2 = __builtin_elementwise_fma(bb[q + 2], E2[q + 2], z2);            \
          z3 = __builtin_elementwise_fma(bb[q + 3], E2[q + 3], z3);            \
        }                                                                      \
        v2f zz = (z0 + z1) + (z2 + z3);                                        \
        Z = zz.x + zz.y;                                                       \
      } else {                                                                 \
        v2f z0 = bb[0] + bb[1], z1 = bb[2] + bb[3];                            \
        v2f z2 = bb[4] + bb[5], z3 = bb[6] + bb[7];                            \
        _Pragma("unroll")                                                      \
        for (int q = 8; q < 24; q += 4) {                                      \
          z0 = z0 + bb[q + 0]; z1 = z1 + bb[q + 1];                            \
          z2 = z2 + bb[q + 2]; z3 = z3 + bb[q + 3];                            \
        }                                                                      \
        v2f zz = (z0 + z1) + (z2 + z3);                                        \
        Z = zz.x + zz.y;                                                       \
      }                                                                        \
      float pnew = Z;                                                          \
      if (RENORM) {                                                            \
        float s48[48];                                                         \
        _Pragma("unroll")                                                      \
        for (int q = 0; q < 24; ++q) { s48[2 * q] = bb[q].x; s48[2 * q + 1] = bb[q].y; } \
        float m16[16];                                                         \
        _Pragma("unroll")                                                      \
        for (int q = 0; q < 16; ++q)                                           \
          m16[q] = fmaxf(fmaxf(s48[3 * q], s48[3 * q + 1]), s48[3 * q + 2]);   \
        float u0 = fmaxf(fmaxf(m16[0], m16[1]), m16[2]);                       \
        float u1 = fmaxf(fmaxf(m16[3], m16[4]), m16[5]);                       \
        float u2 = fmaxf(fmaxf(m16[6], m16[7]), m16[8]);                       \
        float u3 = fmaxf(fmaxf(m16[9], m16[10]), m16[11]);                     \
        float u4 = fmaxf(fmaxf(m16[12], m16[13]), m16[14]);                    \
        float w0 = fmaxf(fmaxf(u0, u1), u2);                                   \
        float w1 = fmaxf(fmaxf(u3, u4), m16[15]);                              \
        float M = fmaxf(w0, w1);                                               \
        float r = __builtin_amdgcn_rcpf(M);                                    \
        pnew = Z * r;                                                          \
        if (t == 0) rbuf[2 * g + (KK >> 2)] = r;                               \
      }                                                                        \
      float pe = pnew * __expf(ebuf[KK] * m1r);                                \
      pls[t] = pe;                                                             \
      if (DOREFILL) ebuf[KK] = ebp[KK * NT];                                   \
    }

    {
      const float* bmp = &bmL[1];
      for (int g = 0; g < 127; ++g) {
        const bool rf = (g < 126);
        FSTEP(0, 0, 1) FSTEP(1, 0, 1) FSTEP(2, 0, 1) FSTEP(3, 1, 1)
        FSTEP(4, 0, 1) FSTEP(5, 0, 1) FSTEP(6, 0, 1)
        if (rf) { FSTEP(7, 1, 1) } else { FSTEP(7, 1, 0) }
        ebp += 8 * NT;
        bmp += 8;
      }
      // tail steps s = 1016..1022 (A = 1017..1023), g fixed = 127 for rbuf idx
      {
        const int g = 127;
        FSTEP(0, 0, 0) FSTEP(1, 0, 0) FSTEP(2, 0, 0) FSTEP(3, 1, 0)
        FSTEP(4, 0, 0) FSTEP(5, 0, 0) FSTEP(6, 0, 0)
      }
    }
#undef FSTEP
    // final step s = 1023: bm_next = 0 -> plain sum + renorm -> pfinal (rbuf[255])
    {
      v4f bb4[12];
#pragma unroll
      for (int q = 0; q < 12; ++q) bb4[q] = *(const v4f*)&pls[4 * q];
      const v2f* bb = (const v2f*)bb4;
      v2f z0 = bb[0] + bb[1], z1 = bb[2] + bb[3];
      v2f z2 = bb[4] + bb[5], z3 = bb[6] + bb[7];
#pragma unroll
      for (int q = 8; q < 24; q += 4) {
        z0 = z0 + bb[q + 0]; z1 = z1 + bb[q + 1];
        z2 = z2 + bb[q + 2]; z3 = z3 + bb[q + 3];
      }
      v2f zz = (z0 + z1) + (z2 + z3);
      float Z = zz.x + zz.y;
      float s48[48];
#pragma unroll
      for (int q = 0; q < 24; ++q) { s48[2 * q] = bb[q].x; s48[2 * q + 1] = bb[q].y; }
      float m16[16];
#pragma unroll
      for (int q = 0; q < 16; ++q)
        m16[q] = fmaxf(fmaxf(s48[3 * q], s48[3 * q + 1]), s48[3 * q + 2]);
      float u0 = fmaxf(fmaxf(m16[0], m16[1]), m16[2]);
      float u1 = fmaxf(fmaxf(m16[3], m16[4]), m16[5]);
      float u2 = fmaxf(fmaxf(m16[6], m16[7]), m16[8]);
      float u3 = fmaxf(fmaxf(m16[9], m16[10]), m16[11]);
      float u4 = fmaxf(fmaxf(m16[12], m16[13]), m16[14]);
      float w0 = fmaxf(fmaxf(u0, u1), u2);
      float w1 = fmaxf(fmaxf(u3, u4), m16[15]);
      float M = fmaxf(w0, w1);
      float r = __builtin_amdgcn_rcpf(M);
      if (t == 0) rbuf[255] = r;
      pfinal = Z * r;
    }
    float ls = 0.f;
#pragma unroll
    for (int k = 0; k < 4; ++k) ls += __logf(rbuf[t + 64 * k]);
#pragma unroll
    for (int d = 1; d < 64; d <<= 1) ls += __shfl_xor(ls, d);
    float v = (t < NT) ? pfinal * __expf(trans[t * TT + (NT + 1)]) : 0.f;
#pragma unroll
    for (int d = 1; d < 64; d <<= 1) v += __shfl_xor(v, d);
    if (t == 0) out[b] = __logf(v) - ls - score[b];
  } else {
    // ---------- Viterbi value pass, pk_add + max3 tree ----------
    v2f T2[24];
#pragma unroll
    for (int q = 0; q < 24; ++q) {
      T2[q].x = trans[(2 * q) * TT + jc];
      T2[q].y = trans[(2 * q + 1) * TT + jc];
    }
    float* Mb = Mbuf + (size_t)b * S_ * NT;
    const float best0 = trans[NT * TT + jc] + tgb[jc];
    pls[t] = best0;
    float ebuf[8];  // ebuf[k] = e[s], s = 8g+1+k
#pragma unroll
    for (int k = 0; k < 8; ++k) ebuf[k] = tgb[(size_t)(1 + k) * NT + jc];
    const float* ebp = tgb + (size_t)9 * NT + jc;
    float* mbp = Mb + NT + jc;

#define VSTEP(KK, DOREFILL)                                                    \
    {                                                                          \
      v4f bb4[12];                                                             \
      _Pragma("unroll")                                                        \
      for (int q = 0; q < 12; ++q) bb4[q] = *(const v4f*)&pls[4 * q];          \
      const v2f* bb = (const v2f*)bb4;                                         \
      v2f c2[24];                                                              \
      _Pragma("unroll")                                                        \
      for (int q = 0; q < 24; ++q) c2[q] = bb[q] + T2[q];                      \
      float s48[48];                                                           \
      _Pragma("unroll")                                                        \
      for (int q = 0; q < 24; ++q) { s48[2 * q] = c2[q].x; s48[2 * q + 1] = c2[q].y; } \
      float m16[16];                                                           \
      _Pragma("unroll")                                                        \
      for (int q = 0; q < 16; ++q)                                             \
        m16[q] = fmaxf(fmaxf(s48[3 * q], s48[3 * q + 1]), s48[3 * q + 2]);     \
      float u0 = fmaxf(fmaxf(m16[0], m16[1]), m16[2]);                         \
      float u1 = fmaxf(fmaxf(m16[3], m16[4]), m16[5]);                         \
      float u2 = fmaxf(fmaxf(m16[6], m16[7]), m16[8]);                         \
      float u3 = fmaxf(fmaxf(m16[9], m16[10]), m16[11]);                       \
      float u4 = fmaxf(fmaxf(m16[12], m16[13]), m16[14]);                      \
      float w0 = fmaxf(fmaxf(u0, u1), u2);                                     \
      float w1 = fmaxf(fmaxf(u3, u4), m16[15]);                                \
      float M = fmaxf(w0, w1);                                                 \
      mbp[KK * NT] = M;                                                        \
      float bnew = M + ebuf[KK];                                               \
      pls[t] = bnew;                                                           \
      if (DOREFILL) ebuf[KK] = ebp[KK * NT];                                   \
    }

    for (int g = 0; g < 127; ++g) {
      const bool rf = (g < 126);
      VSTEP(0, 1) VSTEP(1, 1) VSTEP(2, 1) VSTEP(3, 1)
      VSTEP(4, 1) VSTEP(5, 1) VSTEP(6, 1)
      if (rf) { VSTEP(7, 1) } else { VSTEP(7, 0) }
      mbp += 8 * NT;
      ebp += 8 * NT;
    }
    // tail s = 1017..1023
    VSTEP(0, 0) VSTEP(1, 0) VSTEP(2, 0) VSTEP(3, 0)
    VSTEP(4, 0) VSTEP(5, 0) VSTEP(6, 0)
#undef VSTEP
    // fin recovered from Mbuf (bit-exact: same operands/rounding as in-loop)
    float fin;
    if (L > 0) {
      fin = Mb[(size_t)L * NT + jc] + tgb[(size_t)L * NT + jc];
    } else {
      fin = best0;
    }
    float v = (t < NT) ? (fin + trans[t * TT + (NT + 1)]) : -3.0e38f;
    float M = v;
#pragma unroll
    for (int d = 1; d < 64; d <<= 1) M = fmaxf(M, __shfl_xor(M, d));
    unsigned long long ball = __ballot(v == M);
    int now0 = __ffsll(ball) - 1;
    if (t == 0) nowbuf[b] = now0;
  }
}

// ---------------- K4: parallel argmax recompute (bit-exact replay) ----------------
__global__ __launch_bounds__(256) void k_idx(const float* __restrict__ tg,
                                             const float* __restrict__ Mbuf,
                                             const float* __restrict__ trans,
                                             unsigned char* __restrict__ idxbuf) {
  __shared__ float TshT[NT][NT];  // TshT[j][i] = trans[i][j]
  const int t = threadIdx.x;
  const int b = blockIdx.x;
  for (int k = t; k < NT * NT; k += 256) {
    int i = k / NT, j = k - i * NT;
    TshT[j][i] = trans[i * TT + j];
  }
  __syncthreads();
  const int s = blockIdx.y * 128 + (t >> 1);
  const int jh = (t & 1) * 24;
  if (s < 1) return;
  const float* tgb = tg + (size_t)b * S_ * NT;
  const float* Mb = Mbuf + (size_t)b * S_ * NT;
  float bprev[NT];
  if (s == 1) {
#pragma unroll
    for (int i = 0; i < NT; ++i) bprev[i] = trans[NT * TT + i] + tgb[i];
  } else {
#pragma unroll
    for (int i = 0; i < NT; ++i)
      bprev[i] = Mb[(size_t)(s - 1) * NT + i] + tgb[(size_t)(s - 1) * NT + i];
  }
  unsigned char* ob = idxbuf + ((size_t)b * S_ + s) * NT + jh;
#pragma unroll 4
  for (int jj = 0; jj < 24; ++jj) {
    int j = jh + jj;
    float M = Mb[(size_t)s * NT + j];
    int idx = 0;
#pragma unroll
    for (int i = NT - 1; i >= 0; --i) {
      float cc = bprev[i] + TshT[j][i];
      idx = (cc == M) ? i : idx;
    }
    ob[jj] = (unsigned char)idx;
  }
}

// ---------------- K5: backtrack via chunked pointer jumping ----------------
__global__ __launch_bounds__(1024) void k_btrack(const unsigned char* __restrict__ idxbuf,
                                                 const unsigned char* __restrict__ mask,
                                                 const int* __restrict__ nowbuf,
                                                 float* __restrict__ out) {
  __shared__ unsigned char idxL[S_][NT];
  __shared__ unsigned char mapc[16][NT];
  __shared__ int ELs[16];
  __shared__ int cnt_sh;
  const int t = threadIdx.x;
  const int b = blockIdx.x;
  if (t == 0) cnt_sh = 0;
  __syncthreads();
  {
    const unsigned int* src = (const unsigned int*)(idxbuf + (size_t)b * S_ * NT);
    unsigned int* dst = (unsigned int*)&idxL[t][0];
#pragma unroll
    for (int k = 0; k < 12; ++k) dst[k] = src[(size_t)t * 12 + k];
  }
  int mv = mask[(size_t)b * S_ + t] ? 1 : 0;
  unsigned long long bal = __ballot(mv);
  int wcnt = __popcll(bal);
  if ((t & 63) == 0 && wcnt) atomicAdd(&cnt_sh, wcnt);
  __syncthreads();
  const int L = S_ - 1 - cnt_sh;
  const int now0 = nowbuf[b];
  if (t < 16 * NT) {
    const int c = t / NT;
    const int g = t - c * NT;
    int cur = g;
    const int top = (c == 15) ? (S_ - 1) : (c + 1) * 64;
    const int base = c * 64;
    for (int m = top; m > base; --m) {
      if (m <= L) cur = idxL[m][cur];
    }
    mapc[c][g] = (unsigned char)cur;
  }
  __syncthreads();
  if (t == 0) {
    int e = now0;
    ELs[15] = e;
    for (int c2 = 15; c2 >= 1; --c2) {
      e = mapc[c2][e];
      ELs[c2 - 1] = e;
    }
  }
  __syncthreads();
  float* pathOut = out + B_ + (size_t)b * S_;
  if (t < 16) {
    const int c = t;
    const int top = (c == 15) ? (S_ - 1) : (c + 1) * 64;
    const int base = c * 64;
    int cu = ELs[c];
    for (int m = top; m > base; --m) {
      if (m <= L) cu = idxL[m][cu];
      int pos = m - 1;
      pathOut[pos] = (pos > L) ? -1.0f : (float)cu;
    }
  }
  if (t == 0) pathOut[S_ - 1] = (L == S_ - 1) ? (float)now0 : -1.0f;
}

extern "C" void kernel_launch(void* const* d_in, const int* in_sizes, int n_in,
                              void* d_out, int out_size, void* d_ws, size_t ws_size,
                              hipStream_t stream) {
  const float* F = (const float*)d_in[0];
  const int* y = (const int*)d_in[1];
  const unsigned char* mask = (const unsigned char*)d_in[2];
  const float* Wm = (const float*)d_in[3];
  const float* trans = (const float*)d_in[4];
  float* out = (float*)d_out;

  const size_t NTG = (size_t)B_ * S_ * NT;
  float* tg = (float*)d_ws;
  float* score = tg + NTG;
  float* Mbuf = score + 64;
  int* nowbuf = (int*)(Mbuf + NTG);
  unsigned char* idxbuf = (unsigned char*)(nowbuf + 64);

  k_tagvec<<<dim3((B_ * S_) / 128), dim3(256), 0, stream>>>(F, Wm, tg);
  k_score<<<dim3(B_), dim3(256), 0, stream>>>(tg, y, mask, trans, score);
  k_scan<<<dim3(2 * B_), dim3(64), 0, stream>>>(tg, mask, trans, score, Mbuf, nowbuf, out);
  k_idx<<<dim3(B_, 8), dim3(256), 0, stream>>>(tg, Mbuf, trans, idxbuf);
  k_btrack<<<dim3(B_), dim3(1024), 0, stream>>>(idxbuf, mask, nowbuf, out);
}